// Round 1
// 752.991 us; speedup vs baseline: 1.0064x; 1.0064x over previous
//
#include <hip/hip_runtime.h>

#define N_DIM 12288
#define D_DIM 16
#define TILE_R 256      // rows of A per block (one 64-row band per wave)
#define TILE_C 128      // cols of A per block (2 cols per thread per wave)
#define GROUP  4        // A rows loaded/batched per inner iteration

typedef float f2 __attribute__((ext_vector_type(2)));
typedef float f4 __attribute__((ext_vector_type(4)));

// out[0] = 0 (d_out is poisoned 0xAA before every timed call)
__global__ void zero_kernel(float* __restrict__ out) {
    out[0] = 0.0f;
}

// lmbd1 * (sum|U1| + sum|U2|)
__global__ void l1_kernel(const float* __restrict__ U1,
                          const float* __restrict__ U2,
                          const float* __restrict__ lmbd,
                          float* __restrict__ out) {
    const int M = N_DIM * D_DIM;
    int idx = blockIdx.x * blockDim.x + threadIdx.x;
    int stride = gridDim.x * blockDim.x;
    float s = 0.0f;
    for (int i = idx; i < M; i += stride)
        s += fabsf(U1[i]) + fabsf(U2[i]);
    #pragma unroll
    for (int off = 32; off; off >>= 1)
        s += __shfl_down(s, off, 64);
    __shared__ float ws[4];
    int lane = threadIdx.x & 63;
    int wave = threadIdx.x >> 6;
    if (lane == 0) ws[wave] = s;
    __syncthreads();
    if (threadIdx.x == 0)
        atomicAdd(out, lmbd[0] * (ws[0] + ws[1] + ws[2] + ws[3]));
}

// sum_ij A_ij * (-log_sigmoid(<U1_i, U2_j>)).
// Block: 256(rows) x 128(cols) tile. Thread owns 2 U2 columns in 32 VGPRs.
// U1 tile staged in LDS (16 KB) once -> per-row broadcast ds_read_b128
// (replaces per-row scalar-cache loads, ~120cy vs ~300cy L2 latency).
// A loads batched GROUP rows deep -> 2 KB in flight per wave; at 24 waves/CU
// that is ~48 KB/CU outstanding, enough to sustain HBM peak.
// A in {0,1}: A*log(1+e) == log(1 + A*e), so accumulate the PRODUCT
// p *= fma(A, e, 1.0) over 2*GROUP*2 = 16 elements and take one log2 per
// group (halves transcendental pressure). p <= 2^16, no overflow.
__global__ __launch_bounds__(256, 6)
void loss_kernel(const float* __restrict__ A,
                 const float* __restrict__ U1,
                 const float* __restrict__ U2,
                 float* __restrict__ out) {
    const int t    = threadIdx.x;
    const int lane = t & 63;
    const int wave = t >> 6;
    const int r0   = blockIdx.y * TILE_R;
    const int c0   = blockIdx.x * TILE_C;

    __shared__ float u1s[TILE_R * D_DIM];   // 16 KB

    // Stage U1 rows r0..r0+255 into LDS, coalesced f4 (4 iters x 256 thr).
    {
        const f4* src = (const f4*)U1 + (size_t)r0 * (D_DIM / 4);
        f4* dst = (f4*)u1s;
        #pragma unroll
        for (int i = 0; i < (TILE_R * D_DIM / 4) / 256; ++i)
            dst[i * 256 + t] = src[i * 256 + t];
    }

    // U2 fragment: 2 columns x 16 k in 32 VGPRs. Wave reads a contiguous
    // 8 KB span of U2 (lane l -> rows c0+2l, c0+2l+1): coalesced.
    float u2r[2][D_DIM];
    #pragma unroll
    for (int j = 0; j < 2; ++j) {
        const f4* p = (const f4*)(U2 + (size_t)(c0 + lane * 2 + j) * D_DIM);
        f4 qa = p[0], qb = p[1], qc = p[2], qd = p[3];
        u2r[j][0]  = qa.x; u2r[j][1]  = qa.y; u2r[j][2]  = qa.z; u2r[j][3]  = qa.w;
        u2r[j][4]  = qb.x; u2r[j][5]  = qb.y; u2r[j][6]  = qb.z; u2r[j][7]  = qb.w;
        u2r[j][8]  = qc.x; u2r[j][9]  = qc.y; u2r[j][10] = qc.z; u2r[j][11] = qc.w;
        u2r[j][12] = qd.x; u2r[j][13] = qd.y; u2r[j][14] = qd.z; u2r[j][15] = qd.w;
    }

    __syncthreads();

    const int wr0 = wave * 64;              // wave's first local row
    const float* __restrict__ ap =
        A + (size_t)(r0 + wr0) * N_DIM + (size_t)c0 + lane * 2;

    const float L2E = 1.4426950408889634f;
    float acc = 0.0f;                       // sums log2 of per-group products

    for (int g = 0; g < 64 / GROUP; ++g) {
        // Batch GROUP row-loads first: 4 loads x 8 B/lane in flight per wave.
        f2 av[GROUP];
        #pragma unroll
        for (int r = 0; r < GROUP; ++r)
            av[r] = __builtin_nontemporal_load(
                        (const f2*)(ap + (size_t)r * N_DIM));

        float p0 = 1.0f, p1 = 1.0f;
        #pragma unroll
        for (int r = 0; r < GROUP; ++r) {
            // Wave-uniform LDS address -> broadcast ds_read_b128 x4.
            const f4* uq = (const f4*)(u1s + (wr0 + g * GROUP + r) * D_DIM);
            f4 qa = uq[0], qb = uq[1], qc = uq[2], qd = uq[3];
            float u1v[D_DIM];
            u1v[0]  = qa.x; u1v[1]  = qa.y; u1v[2]  = qa.z; u1v[3]  = qa.w;
            u1v[4]  = qb.x; u1v[5]  = qb.y; u1v[6]  = qb.z; u1v[7]  = qb.w;
            u1v[8]  = qc.x; u1v[9]  = qc.y; u1v[10] = qc.z; u1v[11] = qc.w;
            u1v[12] = qd.x; u1v[13] = qd.y; u1v[14] = qd.z; u1v[15] = qd.w;

            float s0 = 0.0f, s1 = 0.0f;
            #pragma unroll
            for (int k = 0; k < D_DIM; ++k) {
                s0 = fmaf(u1v[k], u2r[0][k], s0);
                s1 = fmaf(u1v[k], u2r[1][k], s1);
            }
            float e0 = __builtin_amdgcn_exp2f(-L2E * s0);
            float e1 = __builtin_amdgcn_exp2f(-L2E * s1);
            // A in {0,1}: term = 1 + A*e  (exact for A=0; == 1+e for A=1)
            p0 *= fmaf(av[r].x, e0, 1.0f);
            p1 *= fmaf(av[r].y, e1, 1.0f);
        }
        acc += __builtin_amdgcn_logf(p0 * p1);   // log2; one per 16 elements
        ap += (size_t)GROUP * N_DIM;
    }

    float part = acc * 0.69314718055994531f;     // ln2: log2 -> ln

    // wave reduce -> block reduce -> one atomic per block
    #pragma unroll
    for (int off = 32; off; off >>= 1)
        part += __shfl_down(part, off, 64);
    __shared__ float wsum[4];
    if (lane == 0) wsum[wave] = part;
    __syncthreads();
    if (t == 0)
        atomicAdd(out, wsum[0] + wsum[1] + wsum[2] + wsum[3]);
}

extern "C" void kernel_launch(void* const* d_in, const int* in_sizes, int n_in,
                              void* d_out, int out_size, void* d_ws, size_t ws_size,
                              hipStream_t stream) {
    const float* A    = (const float*)d_in[0];
    const float* U1   = (const float*)d_in[1];
    const float* U2   = (const float*)d_in[2];
    const float* lmbd = (const float*)d_in[3];
    float* out = (float*)d_out;

    zero_kernel<<<1, 64, 0, stream>>>(out);
    l1_kernel<<<256, 256, 0, stream>>>(U1, U2, lmbd, out);

    dim3 grid(N_DIM / TILE_C, N_DIM / TILE_R);   // 96 x 48 tiles
    loss_kernel<<<grid, 256, 0, stream>>>(A, U1, U2, out);
}

// Round 2
// 743.203 us; speedup vs baseline: 1.0197x; 1.0132x over previous
//
#include <hip/hip_runtime.h>

#define N_DIM 12288
#define D_DIM 16
#define TILE_R 256      // rows of A per block (one 64-row band per wave)
#define TILE_C 128      // cols of A per block (2 cols per thread)
#define GRP    8        // A rows per compute group (pipelined in pairs)

typedef float f2 __attribute__((ext_vector_type(2)));
typedef float f4 __attribute__((ext_vector_type(4)));

// out[0] = 0 (d_out is poisoned 0xAA before every timed call)
__global__ void zero_kernel(float* __restrict__ out) {
    out[0] = 0.0f;
}

// lmbd1 * (sum|U1| + sum|U2|)
__global__ void l1_kernel(const float* __restrict__ U1,
                          const float* __restrict__ U2,
                          const float* __restrict__ lmbd,
                          float* __restrict__ out) {
    const int M = N_DIM * D_DIM;
    int idx = blockIdx.x * blockDim.x + threadIdx.x;
    int stride = gridDim.x * blockDim.x;
    float s = 0.0f;
    for (int i = idx; i < M; i += stride)
        s += fabsf(U1[i]) + fabsf(U2[i]);
    #pragma unroll
    for (int off = 32; off; off >>= 1)
        s += __shfl_down(s, off, 64);
    __shared__ float ws[4];
    int lane = threadIdx.x & 63;
    int wave = threadIdx.x >> 6;
    if (lane == 0) ws[wave] = s;
    __syncthreads();
    if (threadIdx.x == 0)
        atomicAdd(out, lmbd[0] * (ws[0] + ws[1] + ws[2] + ws[3]));
}

// sum_ij A_ij * (-log_sigmoid(<U1_i, U2_j>)).
// Block: 256(rows) x 128(cols). Thread owns 2 U2 columns in 32 VGPRs.
// U1 tile in LDS (16 KB); per-row wave-uniform broadcast ds_read_b128.
// A loads: GRP=8 rows per group, two register buffers (av/bv) software-
// pipelined -> steady-state 8 f2 loads (64 B/lane) in flight per wave,
// 4 KB/wave * 16 waves/CU = 64 KB/CU outstanding (need ~9 KB for HBM peak).
// __launch_bounds__(256,4): 128-VGPR cap. Live set ~100 regs (u2r 32 +
// av 16 + bv 16 + temps) -- round 1's (256,6) capped at 85 and spilled.
// A in {0,1}: A*log(1+e) == log(1 + A*e); accumulate product of
// fma(A,e,1) terms, one log2 per 16 terms (terms in [1,2], p <= 2^8 each).
__global__ __launch_bounds__(256, 4)
void loss_kernel(const float* __restrict__ A,
                 const float* __restrict__ U1,
                 const float* __restrict__ U2,
                 float* __restrict__ out) {
    const int t    = threadIdx.x;
    const int lane = t & 63;
    const int wave = t >> 6;
    const int r0   = blockIdx.y * TILE_R;
    const int c0   = blockIdx.x * TILE_C;

    __shared__ float u1s[TILE_R * D_DIM];   // 16 KB

    // Stage U1 rows r0..r0+255 into LDS, coalesced f4.
    {
        const f4* src = (const f4*)U1 + (size_t)r0 * (D_DIM / 4);
        f4* dst = (f4*)u1s;
        #pragma unroll
        for (int i = 0; i < (TILE_R * D_DIM / 4) / 256; ++i)
            dst[i * 256 + t] = src[i * 256 + t];
    }

    // U2 fragment: 2 columns x 16 k in 32 VGPRs (coalesced f4 loads).
    float u2r[2][D_DIM];
    #pragma unroll
    for (int j = 0; j < 2; ++j) {
        const f4* p = (const f4*)(U2 + (size_t)(c0 + lane * 2 + j) * D_DIM);
        f4 qa = p[0], qb = p[1], qc = p[2], qd = p[3];
        u2r[j][0]  = qa.x; u2r[j][1]  = qa.y; u2r[j][2]  = qa.z; u2r[j][3]  = qa.w;
        u2r[j][4]  = qb.x; u2r[j][5]  = qb.y; u2r[j][6]  = qb.z; u2r[j][7]  = qb.w;
        u2r[j][8]  = qc.x; u2r[j][9]  = qc.y; u2r[j][10] = qc.z; u2r[j][11] = qc.w;
        u2r[j][12] = qd.x; u2r[j][13] = qd.y; u2r[j][14] = qd.z; u2r[j][15] = qd.w;
    }

    __syncthreads();

    const int wr0 = wave * 64;              // wave's first local row
    const float* __restrict__ ap =
        A + (size_t)(r0 + wr0) * N_DIM + (size_t)c0 + lane * 2;

    const float L2E = 1.4426950408889634f;
    float acc = 0.0f;                       // sums log2 of per-group products

    f2 av[GRP], bv[GRP];                    // statically indexed -> registers

#define LOADG(buf, g)                                                         \
    { _Pragma("unroll")                                                       \
      for (int r = 0; r < GRP; ++r)                                           \
          buf[r] = __builtin_nontemporal_load(                                \
              (const f2*)(ap + (size_t)((g) * GRP + r) * N_DIM)); }

#define COMPG(buf, g)                                                         \
    { float p0 = 1.0f, p1 = 1.0f;                                             \
      _Pragma("unroll")                                                       \
      for (int r = 0; r < GRP; ++r) {                                         \
          const f4* uq = (const f4*)(u1s + (wr0 + (g) * GRP + r) * D_DIM);    \
          f4 qa = uq[0], qb = uq[1], qc = uq[2], qd = uq[3];                  \
          float u1v[D_DIM] = {qa.x, qa.y, qa.z, qa.w, qb.x, qb.y, qb.z, qb.w, \
                              qc.x, qc.y, qc.z, qc.w, qd.x, qd.y, qd.z, qd.w};\
          float s0 = 0.0f, s1 = 0.0f;                                         \
          _Pragma("unroll")                                                   \
          for (int k = 0; k < D_DIM; ++k) {                                   \
              s0 = fmaf(u1v[k], u2r[0][k], s0);                               \
              s1 = fmaf(u1v[k], u2r[1][k], s1);                               \
          }                                                                   \
          float e0 = __builtin_amdgcn_exp2f(-L2E * s0);                       \
          float e1 = __builtin_amdgcn_exp2f(-L2E * s1);                       \
          p0 *= fmaf(buf[r].x, e0, 1.0f);                                     \
          p1 *= fmaf(buf[r].y, e1, 1.0f);                                     \
      }                                                                       \
      acc += __builtin_amdgcn_logf(p0 * p1); }   /* v_log_f32 = log2 */

    LOADG(av, 0);
    #pragma unroll
    for (int gg = 0; gg < (64 / GRP) / 2; ++gg) {
        LOADG(bv, 2 * gg + 1);              // prefetch next group
        COMPG(av, 2 * gg);                  // compute current
        if (2 * gg + 2 < 64 / GRP)
            LOADG(av, 2 * gg + 2);          // prefetch next-next
        COMPG(bv, 2 * gg + 1);
    }
#undef LOADG
#undef COMPG

    float part = acc * 0.69314718055994531f;     // ln2: log2 -> ln

    // wave reduce -> block reduce -> one atomic per block
    #pragma unroll
    for (int off = 32; off; off >>= 1)
        part += __shfl_down(part, off, 64);
    __shared__ float wsum[4];
    if (lane == 0) wsum[wave] = part;
    __syncthreads();
    if (t == 0)
        atomicAdd(out, wsum[0] + wsum[1] + wsum[2] + wsum[3]);
}

extern "C" void kernel_launch(void* const* d_in, const int* in_sizes, int n_in,
                              void* d_out, int out_size, void* d_ws, size_t ws_size,
                              hipStream_t stream) {
    const float* A    = (const float*)d_in[0];
    const float* U1   = (const float*)d_in[1];
    const float* U2   = (const float*)d_in[2];
    const float* lmbd = (const float*)d_in[3];
    float* out = (float*)d_out;

    zero_kernel<<<1, 64, 0, stream>>>(out);
    l1_kernel<<<256, 256, 0, stream>>>(U1, U2, lmbd, out);

    dim3 grid(N_DIM / TILE_C, N_DIM / TILE_R);   // 96 x 48 tiles
    loss_kernel<<<grid, 256, 0, stream>>>(A, U1, U2, out);
}